// Round 13
// baseline (415.668 us; speedup 1.0000x reference)
//
#include <hip/hip_runtime.h>
#include <math.h>

#define NN 25000
#define EE 400000
#define GG 64
#define NB 64          // CSR-build blocks (private histogram copies)
#define PL 25024       // plane stride (NN padded to 16B)
#define EPB 6250       // edges per build block (EE/NB exact)

// ---- workspace layout (element offsets, 16B-aligned; NO memset needed) ----
static const int O_CNT   = 0;        // NB*PL ints (per-block histograms)
static const int O_ROWS  = 1601536;  // 25008 ints
static const int O_CUR   = 1626544;  // NB*PL ints (per-block cursor bases)
static const int O_GOFF  = 3228080;  // 72 ints
static const int O_IPART = 3228152;  // 96 f
static const int O_INBN  = 3228248;  // 8 f
static const int O_WS    = 3228256;  // 3*512 f
static const int O_WD    = 3229792;  // 3*512 f
static const int O_WE    = 3231328;  // 32 f
static const int O_BPART = 3231360;  // 128*128 f
static const int O_AB    = 3247744;  // 128 f
static const int O_BSW   = 3247872;  // 16384 f = 32768 bf16 (swizzled W2)
static const int O_CSRC  = 3264256;  // 400000 int
static const int O_CEA   = 3664256;  // 400000 f
static const int O_XS    = 4064256;  // 1.6M f
static const int O_ASRC  = 5664256;  // 200000 f
static const int O_ADST  = 5864256;  // 200000 f
static const int O_AGG   = 6064256;  // 1.6M f
static const int O_X     = 7664256;  // 1.6M f
static const int O_BSWC  = 9264256;  // 2560 f = 5120 bf16
static const int O_BSWA  = 9266816;  // 512 f = 1024 bf16
static const int O_BSUM  = 9267328;  // 104 ints
static const int O_BOFF  = 9267432;  // 104 ints

using f32x4 = __attribute__((ext_vector_type(4))) float;
using sh8   = __attribute__((ext_vector_type(8))) short;  // 8 bf16

__device__ inline short f2bf(float f) {
    unsigned u = __float_as_uint(f);
    unsigned r = (u + 0x7FFFu + ((u >> 16) & 1u)) >> 16;   // RNE to bf16
    return (short)r;
}

// ============ setup (no histogram): instats | goff | prew x3 | bswz | bswc | bswa ============
__global__ void k_pre(const int* __restrict__ batch, const float* __restrict__ x3,
                      const float* w0, const float* we0, const float* as0, const float* ad0, const float* ae0,
                      const float* w1, const float* we1, const float* as1, const float* ad1, const float* ae1,
                      const float* w2, const float* we2, const float* as2, const float* ad2, const float* ae2,
                      int* __restrict__ goff, float* __restrict__ ipart,
                      float* __restrict__ Ws, float* __restrict__ Wd, float* __restrict__ wev,
                      short* __restrict__ bsw, short* __restrict__ bswc, short* __restrict__ bswa) {
    __shared__ float sd[1536];
    int b = blockIdx.x, t = threadIdx.x;
    if (b < 16) {                         // input-BN partial stats
        int ib = b;
        float s[3] = {0,0,0}, q[3] = {0,0,0};
        for (int n = ib * 256 + t; n < NN; n += 16 * 256) {
#pragma unroll
            for (int i = 0; i < 3; i++) { float v = x3[n*3+i]; s[i] += v; q[i] += v*v; }
        }
#pragma unroll
        for (int i = 0; i < 3; i++) { sd[t*6+i] = s[i]; sd[t*6+3+i] = q[i]; }
        __syncthreads();
        for (int off = 128; off > 0; off >>= 1) {
            if (t < off) {
#pragma unroll
                for (int i = 0; i < 6; i++) sd[t*6+i] += sd[(t+off)*6+i];
            }
            __syncthreads();
        }
        if (t < 6) ipart[ib*6 + t] = sd[t];
    } else if (b == 16) {                 // graph offsets (batch sorted)
        if (t <= GG) {
            int g = t, lo = 0, hi = NN;
            while (lo < hi) { int mid = (lo + hi) >> 1; if (batch[mid] < g) lo = mid + 1; else hi = mid; }
            goff[g] = lo;
        }
    } else if (b < 20) {                  // per-layer attention weight fold
        int L = b - 17;
        const float *W, *Wep, *as_, *ad_, *ae_; int INF, CC;
        if (L == 0)      { W = w0; Wep = we0; as_ = as0; ad_ = ad0; ae_ = ae0; INF = 3;  CC = 8;  }
        else if (L == 1) { W = w1; Wep = we1; as_ = as1; ad_ = ad1; ae_ = ae1; INF = 64; CC = 8;  }
        else             { W = w2; Wep = we2; as_ = as2; ad_ = ad2; ae_ = ae2; INF = 64; CC = 64; }
        int HC = 8 * CC;
        for (int tt = t; tt < INF * 8; tt += 256) {
            int i = tt >> 3, h = tt & 7;
            float s = 0.f, d = 0.f;
            for (int c = 0; c < CC; c++) {
                float w = W[i*HC + h*CC + c];
                s += w * as_[h*CC + c];
                d += w * ad_[h*CC + c];
            }
            Ws[L*512 + i*8 + h] = s; Wd[L*512 + i*8 + h] = d;
        }
        if (t < 8) {
            float s = 0.f;
            for (int c = 0; c < CC; c++) s += Wep[t*CC + c] * ae_[t*CC + c];
            wev[L*8 + t] = s;
        }
    } else if (b < 148) {                 // W2 swizzle (128 blocks)
        int idx = (b - 20) * 256 + t;     // < 32768
        int j  = idx & 7;
        int l  = (idx >> 3) & 63;
        int nt = (idx >> 9) & 3;
        int kb = idx >> 11;
        int k = kb*32 + (l >> 4)*4 + (j & 3) + 16*(j >> 2);
        int c = nt*16 + (l & 15);
        int h = k >> 6, i = k & 63;
        bsw[idx] = f2bf(w2[i*512 + h*64 + c]);
    } else if (b < 168) {                 // layer-1 cat [W1|Ws1|Wd1] swizzle (20 blocks)
        int idx = (b - 148) * 256 + t;    // < 5120
        int j  = idx & 7;
        int l  = (idx >> 3) & 63;
        int r2 = idx >> 9;                // 0..9
        int nt = r2 % 5, kb = r2 / 5;
        int k = kb*32 + (l >> 4)*4 + (j & 3) + 16*(j >> 2);
        int c = nt*16 + (l & 15);
        float val;
        if (c < 64) val = w1[k*64 + c];
        else {
            int h = (c - 64) & 7;
            const float* aa = (c < 72) ? as1 : ad1;
            float s = 0.f;
            for (int cc = 0; cc < 8; cc++) s += w1[k*64 + h*8 + cc] * aa[h*8 + cc];
            val = s;
        }
        bswc[idx] = f2bf(val);
    } else {                              // layer-2 [Ws2|Wd2] swizzle (4 blocks)
        int idx = (b - 168) * 256 + t;    // < 1024
        int j  = idx & 7;
        int l  = (idx >> 3) & 63;
        int kb = idx >> 9;                // 0..1
        int k = kb*32 + (l >> 4)*4 + (j & 3) + 16*(j >> 2);
        int c = l & 15;
        int h = c & 7;
        const float* aa = (c < 8) ? as2 : ad2;
        float s = 0.f;
        for (int cc = 0; cc < 64; cc++) s += w2[k*512 + h*64 + cc] * aa[h*64 + cc];
        bswa[idx] = f2bf(s);
    }
}

// ============ edge histogram: per-block private LDS histogram, zero global atomics ============
__global__ __launch_bounds__(256) void k_hist(const int* __restrict__ ei, int* __restrict__ cnt) {
    __shared__ int hb[PL];
    int t = threadIdx.x, b = blockIdx.x;
    for (int i = t; i < PL; i += 256) hb[i] = 0;
    __syncthreads();
    int e0 = b * EPB;
    for (int e = e0 + t; e < e0 + EPB; e += 256)
        atomicAdd(&hb[ei[EE + e]], 1);
    __syncthreads();
    for (int i = t; i < NN; i += 256) cnt[b * PL + i] = hb[i];
}

// ============ hierarchical degree scan ============
__global__ void k_scan1(const int* __restrict__ cnt, int* __restrict__ rows,
                        int* __restrict__ bsum) {
    int t = threadIdx.x, b = blockIdx.x;
    int i = b * 256 + t;
    int v = 0;
    if (i < NN) {
        for (int r = 0; r < NB; r++) v += cnt[r * PL + i];
    }
    __shared__ int sd[256];
    sd[t] = v; __syncthreads();
    for (int off = 1; off < 256; off <<= 1) {
        int x = (t >= off) ? sd[t - off] : 0;
        __syncthreads();
        sd[t] += x;
        __syncthreads();
    }
    if (i < NN) rows[i] = sd[t] - v;     // exclusive local scan
    if (t == 255) bsum[b] = sd[255];
}

__global__ void k_scan2(const int* __restrict__ bsum, int* __restrict__ boff,
                        const float* __restrict__ ipart, float* __restrict__ inbn) {
    int t = threadIdx.x;
    if (t == 0) {
        int run = 0;
        for (int b = 0; b < 98; b++) { int v = bsum[b]; boff[b] = run; run += v; }
    }
    if (t < 6) { float s = 0.f; for (int b = 0; b < 16; b++) s += ipart[b*6 + t]; inbn[t] = s; }
}

__global__ void k_scan3(const int* __restrict__ boff, const int* __restrict__ cnt,
                        int* __restrict__ rows, int* __restrict__ cur) {
    int t = threadIdx.x, b = blockIdx.x;
    int i = b * 256 + t;
    if (i < NN) {
        int run = rows[i] + boff[b];
        rows[i] = run;
        for (int r = 0; r < NB; r++) {
            cur[r * PL + i] = run;
            run += cnt[r * PL + i];
        }
    }
    if (b == 0 && t == 0) rows[NN] = EE;
}

// ============ CSR fill: LDS cursor per block, zero global atomics ============
__global__ __launch_bounds__(256) void k_fill(const int* __restrict__ ei, const float* __restrict__ ea,
                       const int* __restrict__ cur, int* __restrict__ csrc,
                       float* __restrict__ cea) {
    __shared__ int lc[PL];
    int t = threadIdx.x, b = blockIdx.x;
    for (int i = t; i < NN; i += 256) lc[i] = cur[b * PL + i];
    __syncthreads();
    int e0 = b * EPB;
    for (int e = e0 + t; e < e0 + EPB; e += 256) {
        int s = ei[e], d = ei[EE + e];
        int pos = atomicAdd(&lc[d], 1);
        csrc[pos] = s; cea[pos] = ea[e];
    }
}

// ============ layer-0 projection (input BN fused, in=3) ============
__global__ void k_proj0(const float* __restrict__ x, const float* __restrict__ sums,
                        const float* __restrict__ g, const float* __restrict__ b,
                        const float* __restrict__ W0,
                        const float* __restrict__ Ws, const float* __restrict__ Wd,
                        float* __restrict__ xs, float* __restrict__ asrc, float* __restrict__ adst) {
    int idx = blockIdx.x * 256 + threadIdx.x;
    if (idx >= NN * 64) return;
    int n = idx >> 6, j = idx & 63;
    float xn[3];
#pragma unroll
    for (int i = 0; i < 3; i++) {
        float m = sums[i] * (1.0f / NN);
        float v = sums[3+i] * (1.0f / NN) - m*m;
        xn[i] = (x[n*3+i] - m) * rsqrtf(v + 1e-5f) * g[i] + b[i];
    }
    float a = 0.f;
#pragma unroll
    for (int i = 0; i < 3; i++) a += xn[i] * W0[i*64 + j];
    xs[n*64 + j] = a;
    if (j < 16) {
        const float* WA = (j < 8) ? Ws : Wd;
        int h = j & 7;
        float s = 0.f;
#pragma unroll
        for (int i = 0; i < 3; i++) s += xn[i] * WA[i*8 + h];
        if (j < 8) asrc[n*8 + h] = s; else adst[n*8 + h] = s;
    }
}

// ============ fused edge-softmax + aggregation, C=8 (layers 0,1), chunked+4x ============
__global__ void k_agg8f(const int* __restrict__ rows, const int* __restrict__ csrc,
                        const float* __restrict__ cea,
                        const float* __restrict__ asrc, const float* __restrict__ adst,
                        const float* __restrict__ wev,
                        const float* __restrict__ xs, float* __restrict__ agg) {
    int lane = threadIdx.x & 63;
    int d = (blockIdx.x * blockDim.x + threadIdx.x) >> 6;
    if (d >= NN) return;
    int h = lane >> 3;
    float adh = adst[d*8 + h];
    float wh  = wev[h];
    int rs = rows[d], re = rows[d+1];
    float acc = 0.f, den = 0.f;
    for (int c0 = rs; c0 < re; c0 += 64) {
        int cnt = re - c0; if (cnt > 64) cnt = 64;
        int ii = c0 + (lane < cnt ? lane : 0);
        int es = csrc[ii];
        float ef = cea[ii];
        int j = 0;
        for (; j + 3 < cnt; j += 4) {
            int s0 = __shfl(es, j),   s1 = __shfl(es, j+1);
            int s2 = __shfl(es, j+2), s3 = __shfl(es, j+3);
            float a0 = __shfl(ef, j),   a1 = __shfl(ef, j+1);
            float a2 = __shfl(ef, j+2), a3 = __shfl(ef, j+3);
            float l0 = asrc[s0*8+h], l1 = asrc[s1*8+h];
            float l2 = asrc[s2*8+h], l3 = asrc[s3*8+h];
            float x0 = xs[s0*64+lane], x1 = xs[s1*64+lane];
            float x2 = xs[s2*64+lane], x3 = xs[s3*64+lane];
            l0 += adh + a0*wh; l1 += adh + a1*wh;
            l2 += adh + a2*wh; l3 += adh + a3*wh;
            l0 = fmaxf(l0, 0.2f*l0); l1 = fmaxf(l1, 0.2f*l1);
            l2 = fmaxf(l2, 0.2f*l2); l3 = fmaxf(l3, 0.2f*l3);
            float e0 = __expf(l0), e1 = __expf(l1), e2 = __expf(l2), e3 = __expf(l3);
            den += (e0 + e1) + (e2 + e3);
            acc += e0*x0; acc += e1*x1; acc += e2*x2; acc += e3*x3;
        }
        for (; j < cnt; j++) {
            int s = __shfl(es, j);
            float a = __shfl(ef, j);
            float l = asrc[s*8+h] + adh + a*wh;
            l = fmaxf(l, 0.2f*l);
            float e = __expf(l);
            den += e;
            acc += e * xs[s*64+lane];
        }
    }
    agg[d*64 + lane] = acc / fmaxf(den, 1e-16f);
}

// ============ layer-1 projection via MFMA: [xb | asrc | adst] = elu(bn(agg)) @ [W1|Ws1|Wd1] ============
__global__ void k_proj1m(const float* __restrict__ agg, const float* __restrict__ ab,
                         const short* __restrict__ bswc,
                         float* __restrict__ xb, float* __restrict__ xs,
                         float* __restrict__ asrc, float* __restrict__ adst) {
    int l = threadIdx.x & 63;
    int wid = (blockIdx.x * blockDim.x + threadIdx.x) >> 6;
    int n0 = wid * 16;
    if (n0 >= NN) return;
    int ra = n0 + (l & 15); if (ra > NN-1) ra = NN-1;
    int kq = (l >> 4) * 4;
    const sh8* Bs = (const sh8*)bswc;
    sh8 af0, af1;
#pragma unroll
    for (int kb = 0; kb < 2; kb++) {
        int c0 = kb*32 + kq;
        float4 a0 = *(const float4*)&agg[ra*64 + c0];
        float4 a1 = *(const float4*)&agg[ra*64 + c0 + 16];
        float4 sc0 = *(const float4*)&ab[c0];
        float4 sh0 = *(const float4*)&ab[64 + c0];
        float4 sc1 = *(const float4*)&ab[c0 + 16];
        float4 sh1 = *(const float4*)&ab[64 + c0 + 16];
        float o[8];
        o[0] = a0.x*sc0.x + sh0.x; o[1] = a0.y*sc0.y + sh0.y;
        o[2] = a0.z*sc0.z + sh0.z; o[3] = a0.w*sc0.w + sh0.w;
        o[4] = a1.x*sc1.x + sh1.x; o[5] = a1.y*sc1.y + sh1.y;
        o[6] = a1.z*sc1.z + sh1.z; o[7] = a1.w*sc1.w + sh1.w;
#pragma unroll
        for (int u = 0; u < 8; u++) o[u] = (o[u] > 0.f) ? o[u] : (__expf(o[u]) - 1.f);
        float4 w0v = {o[0],o[1],o[2],o[3]}, w1v = {o[4],o[5],o[6],o[7]};
        *(float4*)&xb[ra*64 + c0]      = w0v;
        *(float4*)&xb[ra*64 + c0 + 16] = w1v;
        sh8 af;
#pragma unroll
        for (int u = 0; u < 8; u++) af[u] = f2bf(o[u]);
        if (kb == 0) af0 = af; else af1 = af;
    }
    f32x4 acc[5];
#pragma unroll
    for (int nt = 0; nt < 5; nt++) acc[nt] = (f32x4){0,0,0,0};
#pragma unroll
    for (int nt = 0; nt < 5; nt++) {
        acc[nt] = __builtin_amdgcn_mfma_f32_16x16x32_bf16(af0, Bs[nt*64 + l], acc[nt], 0, 0, 0);
        acc[nt] = __builtin_amdgcn_mfma_f32_16x16x32_bf16(af1, Bs[(5+nt)*64 + l], acc[nt], 0, 0, 0);
    }
    int rbase = n0 + (l >> 4) * 4, cb = l & 15;
#pragma unroll
    for (int r = 0; r < 4; r++) {
        int n = rbase + r;
        if (n >= NN) break;
#pragma unroll
        for (int nt = 0; nt < 4; nt++) xs[n*64 + nt*16 + cb] = acc[nt][r];
        if (cb < 8) asrc[n*8 + cb] = acc[4][r];
        else        adst[n*8 + (cb-8)] = acc[4][r];
    }
}

// ============ fused BN1-apply + residual + layer-2 attention logits (MFMA) ============
__global__ void k_bnattn(const float* __restrict__ agg, const float* __restrict__ ab,
                         const short* __restrict__ bswa,
                         float* __restrict__ xb,
                         float* __restrict__ asrc, float* __restrict__ adst) {
    int l = threadIdx.x & 63;
    int wid = (blockIdx.x * blockDim.x + threadIdx.x) >> 6;
    int n0 = wid * 16;
    if (n0 >= NN) return;
    int ra = n0 + (l & 15); if (ra > NN-1) ra = NN-1;
    int kq = (l >> 4) * 4;
    const sh8* Bs = (const sh8*)bswa;
    sh8 af0, af1;
#pragma unroll
    for (int kb = 0; kb < 2; kb++) {
        int c0 = kb*32 + kq;
        float4 a0 = *(const float4*)&agg[ra*64 + c0];
        float4 a1 = *(const float4*)&agg[ra*64 + c0 + 16];
        float4 x0 = *(const float4*)&xb[ra*64 + c0];
        float4 x1 = *(const float4*)&xb[ra*64 + c0 + 16];
        float4 sc0 = *(const float4*)&ab[c0];
        float4 sh0 = *(const float4*)&ab[64 + c0];
        float4 sc1 = *(const float4*)&ab[c0 + 16];
        float4 sh1 = *(const float4*)&ab[64 + c0 + 16];
        float o[8];
        o[0] = a0.x*sc0.x + sh0.x; o[1] = a0.y*sc0.y + sh0.y;
        o[2] = a0.z*sc0.z + sh0.z; o[3] = a0.w*sc0.w + sh0.w;
        o[4] = a1.x*sc1.x + sh1.x; o[5] = a1.y*sc1.y + sh1.y;
        o[6] = a1.z*sc1.z + sh1.z; o[7] = a1.w*sc1.w + sh1.w;
#pragma unroll
        for (int u = 0; u < 8; u++) o[u] = (o[u] > 0.f) ? o[u] : (__expf(o[u]) - 1.f);
        o[0] += x0.x; o[1] += x0.y; o[2] += x0.z; o[3] += x0.w;
        o[4] += x1.x; o[5] += x1.y; o[6] += x1.z; o[7] += x1.w;
        float4 w0v = {o[0],o[1],o[2],o[3]}, w1v = {o[4],o[5],o[6],o[7]};
        *(float4*)&xb[ra*64 + c0]      = w0v;
        *(float4*)&xb[ra*64 + c0 + 16] = w1v;
        sh8 af;
#pragma unroll
        for (int u = 0; u < 8; u++) af[u] = f2bf(o[u]);
        if (kb == 0) af0 = af; else af1 = af;
    }
    f32x4 acc = {0,0,0,0};
    acc = __builtin_amdgcn_mfma_f32_16x16x32_bf16(af0, Bs[l],      acc, 0, 0, 0);
    acc = __builtin_amdgcn_mfma_f32_16x16x32_bf16(af1, Bs[64 + l], acc, 0, 0, 0);
    int rbase = n0 + (l >> 4) * 4, cb = l & 15;
#pragma unroll
    for (int r = 0; r < 4; r++) {
        int n = rbase + r;
        if (n >= NN) break;
        if (cb < 8) asrc[n*8 + cb] = acc[r];
        else        adst[n*8 + (cb-8)] = acc[r];
    }
}

// ============ layer-2 fused: edge-softmax + aggregate + MFMA projection ============
// 512 threads = 8 waves/block, 2 nodes per wave; 4x edge unroll for ILP.
// 4 blocks/CU resident (LDS 16.9KB, VGPR<=64) -> full-occupancy latency hiding.
__global__ __launch_bounds__(512) void k_l2f(
        const int* __restrict__ rows, const int* __restrict__ csrc,
        const float* __restrict__ cea,
        const float* __restrict__ asrc, const float* __restrict__ adst,
        const float* __restrict__ wev,
        const float* __restrict__ x, const short* __restrict__ bsw,
        float* __restrict__ agg) {
    __shared__ short zl[16 * 520];
    int t = threadIdx.x, lane = t & 63, wv = t >> 6;   // wv in 0..7
    int blk = blockIdx.x;
    int h = lane >> 3;
    float wh = wev[h];
    const float4* x4 = (const float4*)x;
    int fo   = (lane & 7) * 2;
    int kb_w = lane >> 2;
    int qd0  = 2 * (lane & 1);
    int jhi  = 4 * ((lane >> 1) & 1);
    for (int q = 0; q < 2; q++) {
        int r = wv * 2 + q;
        int d = blk * 16 + r;
        float acc[8] = {0,0,0,0,0,0,0,0};
        float den = 0.f;
        if (d < NN) {
            float adh = adst[d*8 + h];
            int rs = rows[d], re = rows[d+1];
            for (int c0 = rs; c0 < re; c0 += 64) {
                int cnt = re - c0; if (cnt > 64) cnt = 64;
                int ii = c0 + (lane < cnt ? lane : 0);
                int es = csrc[ii];
                float ef = cea[ii];
                int j = 0;
                for (; j + 3 < cnt; j += 4) {
                    int s0 = __shfl(es, j),   s1 = __shfl(es, j+1);
                    int s2 = __shfl(es, j+2), s3 = __shfl(es, j+3);
                    float a0 = __shfl(ef, j),   a1 = __shfl(ef, j+1);
                    float a2 = __shfl(ef, j+2), a3 = __shfl(ef, j+3);
                    float l0 = asrc[s0*8+h], l1 = asrc[s1*8+h];
                    float l2 = asrc[s2*8+h], l3 = asrc[s3*8+h];
                    float4 u0 = x4[s0*16 + fo], u1 = x4[s0*16 + fo + 1];
                    float4 v0 = x4[s1*16 + fo], v1 = x4[s1*16 + fo + 1];
                    float4 w0 = x4[s2*16 + fo], w1 = x4[s2*16 + fo + 1];
                    float4 y0 = x4[s3*16 + fo], y1 = x4[s3*16 + fo + 1];
                    l0 += adh + a0*wh; l1 += adh + a1*wh;
                    l2 += adh + a2*wh; l3 += adh + a3*wh;
                    l0 = fmaxf(l0, 0.2f*l0); l1 = fmaxf(l1, 0.2f*l1);
                    l2 = fmaxf(l2, 0.2f*l2); l3 = fmaxf(l3, 0.2f*l3);
                    float e0 = __expf(l0), e1 = __expf(l1);
                    float e2 = __expf(l2), e3 = __expf(l3);
                    den += (e0 + e1) + (e2 + e3);
                    acc[0] += e0*u0.x + e1*v0.x; acc[0] += e2*w0.x + e3*y0.x;
                    acc[1] += e0*u0.y + e1*v0.y; acc[1] += e2*w0.y + e3*y0.y;
                    acc[2] += e0*u0.z + e1*v0.z; acc[2] += e2*w0.z + e3*y0.z;
                    acc[3] += e0*u0.w + e1*v0.w; acc[3] += e2*w0.w + e3*y0.w;
                    acc[4] += e0*u1.x + e1*v1.x; acc[4] += e2*w1.x + e3*y1.x;
                    acc[5] += e0*u1.y + e1*v1.y; acc[5] += e2*w1.y + e3*y1.y;
                    acc[6] += e0*u1.z + e1*v1.z; acc[6] += e2*w1.z + e3*y1.z;
                    acc[7] += e0*u1.w + e1*v1.w; acc[7] += e2*w1.w + e3*y1.w;
                }
                for (; j < cnt; j++) {
                    int s = __shfl(es, j);
                    float a = __shfl(ef, j);
                    float l = asrc[s*8+h] + adh + a*wh;
                    l = fmaxf(l, 0.2f*l);
                    float e = __expf(l);
                    den += e;
                    float4 u0 = x4[s*16 + fo], u1 = x4[s*16 + fo + 1];
                    acc[0] += e*u0.x; acc[1] += e*u0.y; acc[2] += e*u0.z; acc[3] += e*u0.w;
                    acc[4] += e*u1.x; acc[5] += e*u1.y; acc[6] += e*u1.z; acc[7] += e*u1.w;
                }
            }
        }
        float inv = 1.0f / fmaxf(den, 1e-16f);
        short4 lo, hi;
        lo.x = f2bf(acc[0]*inv); lo.y = f2bf(acc[1]*inv);
        lo.z = f2bf(acc[2]*inv); lo.w = f2bf(acc[3]*inv);
        hi.x = f2bf(acc[4]*inv); hi.y = f2bf(acc[5]*inv);
        hi.z = f2bf(acc[6]*inv); hi.w = f2bf(acc[7]*inv);
        *(short4*)&zl[kb_w*520 + (r + 16*qd0)*8 + jhi]     = lo;
        *(short4*)&zl[kb_w*520 + (r + 16*(qd0+1))*8 + jhi] = hi;
    }
    __syncthreads();
    if (wv < 4) {
        const sh8* Bs = (const sh8*)bsw;
        f32x4 oacc = {0,0,0,0};
        for (int kb = 0; kb < 16; kb++) {
            sh8 a = *(const sh8*)&zl[kb*520 + lane*8];
            sh8 bf = Bs[(kb*4 + wv)*64 + lane];
            oacc = __builtin_amdgcn_mfma_f32_16x16x32_bf16(a, bf, oacc, 0, 0, 0);
        }
        int row = blk*16 + (lane >> 4) * 4;
        int col = wv*16 + (lane & 15);
#pragma unroll
        for (int rr = 0; rr < 4; rr++) {
            int n = row + rr;
            if (n < NN) agg[(size_t)n*64 + col] = oacc[rr] * 0.125f;
        }
    }
}

// ============ BN stats partials (bias cancels in training-mode BN) ============
__global__ void k_bnstats(const float* __restrict__ agg, float* __restrict__ part) {
    int t = threadIdx.x;
    int c = t & 63;
    int r0 = blockIdx.x * 4 + (t >> 6);
    float s = 0.f, q = 0.f;
    for (int n = r0; n < NN; n += gridDim.x * 4) {
        float y = agg[n*64 + c];
        s += y; q += y*y;
    }
    __shared__ float sd[512];
    sd[t] = s; sd[256 + t] = q;
    __syncthreads();
    if (t < 128) { sd[t] += sd[t+128]; sd[256+t] += sd[256+t+128]; }
    __syncthreads();
    if (t < 64) {
        part[blockIdx.x*128 + t]      = sd[t] + sd[t+64];
        part[blockIdx.x*128 + 64 + t] = sd[256+t] + sd[256+t+64];
    }
}

// ============ BN finalize ============
__global__ void k_bnfin(const float* __restrict__ part, const float* __restrict__ gam,
                        const float* __restrict__ bet, float* __restrict__ ab) {
    int c = threadIdx.x;
    if (c >= 64) return;
    float s = 0.f, q = 0.f;
    for (int b = 0; b < 128; b++) { s += part[b*128 + c]; q += part[b*128 + 64 + c]; }
    float m = s * (1.0f / NN);
    float v = q * (1.0f / NN) - m*m;
    float a = gam[c] * rsqrtf(v + 1e-5f);
    ab[c] = a;
    ab[64 + c] = bet[c] - m * a;
}

// ============ fused: BN2-apply + residual + dual pooling + MLP head ============
__global__ void k_poolmlp(const float* __restrict__ xb, const float* __restrict__ agg,
                          const float* __restrict__ ab, const int* __restrict__ goff,
                          const float* __restrict__ fc1w, const float* __restrict__ fc1b,
                          const float* __restrict__ fc2w, const float* __restrict__ fc2b,
                          const float* __restrict__ fgw, const float* __restrict__ fgb,
                          const float* __restrict__ fbw, const float* __restrict__ fbb,
                          float* __restrict__ out) {
    int g = blockIdx.x, t = threadIdx.x;
    int c = t & 63, r = t >> 6;
    float a = ab[c], sh = ab[64 + c];
    int st = goff[g], en = goff[g+1];
    float s = 0.f, mx = -INFINITY;
    for (int n = st + r; n < en; n += 4) {
        float o = agg[n*64 + c] * a + sh;
        o = (o > 0.f) ? o : (__expf(o) - 1.0f);
        float v = xb[n*64 + c] + o;
        s += v; mx = fmaxf(mx, v);
    }
    __shared__ float sd[512];
    __shared__ float sg[128], s1[128], s2[64];
    sd[t] = s; sd[256 + t] = mx;
    __syncthreads();
    if (t < 128) { sd[t] += sd[t+128]; sd[256+t] = fmaxf(sd[256+t], sd[256+t+128]); }
    __syncthreads();
    if (t < 64) {
        float cnt = (float)(en - st);
        sg[t]      = (sd[t] + sd[t+64]) / fmaxf(cnt, 1.0f);
        sg[64 + t] = fmaxf(sd[256+t], sd[256+t+64]);
    }
    __syncthreads();
    if (t < 128) {
        float av = fc1b[t];
        for (int i = 0; i < 128; i++) av += sg[i] * fc1w[i*128 + t];
        s1[t] = (av > 0.f) ? av : (__expf(av) - 1.f);
    }
    __syncthreads();
    if (t < 64) {
        float bv = fc2b[t];
        for (int i = 0; i < 128; i++) bv += s1[i] * fc2w[i*64 + t];
        s2[t] = (bv > 0.f) ? bv : (__expf(bv) - 1.f);
    }
    __syncthreads();
    if (t == 0) {
        float ga = fgb[0], be = fbb[0];
        for (int i = 0; i < 64; i++) { ga += s2[i] * fgw[i]; be += s2[i] * fbw[i]; }
        out[g*2 + 0] = ga;
        out[g*2 + 1] = be;
    }
}

extern "C" void kernel_launch(void* const* d_in, const int* in_sizes, int n_in,
                              void* d_out, int out_size, void* d_ws, size_t ws_size,
                              hipStream_t stream) {
    (void)in_sizes; (void)n_in; (void)out_size; (void)ws_size;
    const float* x3    = (const float*)d_in[0];
    const int*   ei    = (const int*)d_in[1];
    const float* ea    = (const float*)d_in[2];
    const int*   batch = (const int*)d_in[3];
    const float* ing   = (const float*)d_in[4];
    const float* inb   = (const float*)d_in[5];
    const float* w0    = (const float*)d_in[6];
    const float* we0   = (const float*)d_in[7];
    const float* as0   = (const float*)d_in[8];
    const float* ad0   = (const float*)d_in[9];
    const float* ae0   = (const float*)d_in[10];
    const float* bng0  = (const float*)d_in[12];
    const float* bnb0  = (const float*)d_in[13];
    const float* w1    = (const float*)d_in[14];
    const float* we1   = (const float*)d_in[15];
    const float* as1   = (const float*)d_in[16];
    const float* ad1   = (const float*)d_in[17];
    const float* ae1   = (const float*)d_in[18];
    const float* bng1  = (const float*)d_in[20];
    const float* bnb1  = (const float*)d_in[21];
    const float* w2    = (const float*)d_in[22];
    const float* we2   = (const float*)d_in[23];
    const float* as2   = (const float*)d_in[24];
    const float* ad2   = (const float*)d_in[25];
    const float* ae2   = (const float*)d_in[26];
    const float* bng2  = (const float*)d_in[28];
    const float* bnb2  = (const float*)d_in[29];
    const float* fc1w  = (const float*)d_in[30];
    const float* fc1b  = (const float*)d_in[31];
    const float* fc2w  = (const float*)d_in[32];
    const float* fc2b  = (const float*)d_in[33];
    const float* fgw   = (const float*)d_in[34];
    const float* fgb   = (const float*)d_in[35];
    const float* fbw   = (const float*)d_in[36];
    const float* fbb   = (const float*)d_in[37];

    float* fws = (float*)d_ws;
    int*   iws = (int*)d_ws;
    int*   cnt   = iws + O_CNT;
    int*   rows  = iws + O_ROWS;
    int*   cur   = iws + O_CUR;
    int*   goff  = iws + O_GOFF;
    float* ipart = fws + O_IPART;
    float* inbn  = fws + O_INBN;
    float* Ws    = fws + O_WS;
    float* Wd    = fws + O_WD;
    float* wev   = fws + O_WE;
    float* bpart = fws + O_BPART;
    float* ab    = fws + O_AB;
    short* bsw   = (short*)(fws + O_BSW);
    int*   csrc  = iws + O_CSRC;
    float* cea   = fws + O_CEA;
    float* xs    = fws + O_XS;
    float* asrc  = fws + O_ASRC;
    float* adst  = fws + O_ADST;
    float* agg   = fws + O_AGG;
    float* xb    = fws + O_X;
    short* bswc  = (short*)(fws + O_BSWC);
    short* bswa  = (short*)(fws + O_BSWA);
    int*   bsum  = iws + O_BSUM;
    int*   boff  = iws + O_BOFF;

    k_pre<<<172, 256, 0, stream>>>(batch, x3,
                                   w0, we0, as0, ad0, ae0,
                                   w1, we1, as1, ad1, ae1,
                                   w2, we2, as2, ad2, ae2,
                                   goff, ipart, Ws, Wd, wev, bsw, bswc, bswa);
    k_hist<<<NB, 256, 0, stream>>>(ei, cnt);
    k_scan1<<<98, 256, 0, stream>>>(cnt, rows, bsum);
    k_scan2<<<1, 64, 0, stream>>>(bsum, boff, ipart, inbn);
    k_scan3<<<98, 256, 0, stream>>>(boff, cnt, rows, cur);
    k_fill<<<NB, 256, 0, stream>>>(ei, ea, cur, csrc, cea);

    const int nblk64 = (NN * 64 + 255) / 256;   // 6250
    const int wblk16 = ((NN + 15) / 16 + 3) / 4; // 391 blocks of 4 waves (16 nodes/wave)

    // ---- layer 0 ----
    k_proj0<<<nblk64, 256, 0, stream>>>(x3, inbn, ing, inb, w0, Ws, Wd, xs, asrc, adst);
    k_agg8f<<<nblk64, 256, 0, stream>>>(rows, csrc, cea, asrc, adst, wev, xs, agg);
    k_bnstats<<<128, 256, 0, stream>>>(agg, bpart);
    k_bnfin<<<1, 64, 0, stream>>>(bpart, bng0, bnb0, ab);

    // ---- layer 1 (BN0-apply + xb + projection + logits via MFMA) ----
    k_proj1m<<<wblk16, 256, 0, stream>>>(agg, ab, bswc, xb, xs, asrc, adst);
    k_agg8f<<<nblk64, 256, 0, stream>>>(rows, csrc, cea, asrc, adst, wev + 8, xs, agg);
    k_bnstats<<<128, 256, 0, stream>>>(agg, bpart);
    k_bnfin<<<1, 64, 0, stream>>>(bpart, bng1, bnb1, ab);

    // ---- layer 2 (BN1-apply + residual + logits fused; then fused agg+MFMA, 8 waves/block) ----
    k_bnattn<<<wblk16, 256, 0, stream>>>(agg, ab, bswa, xb, asrc, adst);
    k_l2f<<<(NN + 15) / 16, 512, 0, stream>>>(rows, csrc, cea, asrc, adst, wev + 16,
                                              xb, bsw, agg);
    k_bnstats<<<128, 256, 0, stream>>>(agg, bpart);
    k_bnfin<<<1, 64, 0, stream>>>(bpart, bng2, bnb2, ab);

    // ---- BN2-apply + residual + pooling + MLP head ----
    k_poolmlp<<<GG, 256, 0, stream>>>(xb, agg, ab, goff, fc1w, fc1b, fc2w, fc2b,
                                      fgw, fgb, fbw, fbb, (float*)d_out);
}

// Round 14
// 408.173 us; speedup vs baseline: 1.0184x; 1.0184x over previous
//
#include <hip/hip_runtime.h>
#include <math.h>

#define NN 25000
#define EE 400000
#define GG 64
#define NB 64          // CSR-build blocks (private histogram copies)
#define PL 25024       // plane stride (NN padded to 16B)
#define EPB 6250       // edges per build block (EE/NB exact)

// ---- workspace layout (element offsets, 16B-aligned; NO memset needed) ----
static const int O_CNT   = 0;        // NB*PL ints (per-block histograms)
static const int O_ROWS  = 1601536;  // 25008 ints
static const int O_CUR   = 1626544;  // NB*PL ints (per-block cursor bases)
static const int O_GOFF  = 3228080;  // 72 ints
static const int O_IPART = 3228152;  // 96 f
static const int O_INBN  = 3228248;  // 8 f
static const int O_WS    = 3228256;  // 3*512 f
static const int O_WD    = 3229792;  // 3*512 f
static const int O_WE    = 3231328;  // 32 f
static const int O_BPART = 3231360;  // 128*128 f
static const int O_AB    = 3247744;  // 128 f
static const int O_BSW   = 3247872;  // 16384 f = 32768 bf16 (swizzled W2)
static const int O_CSRC  = 3264256;  // 400000 int
static const int O_CEA   = 3664256;  // 400000 f
static const int O_XS    = 4064256;  // 800000 f region = 1.6M bf16 (xs, layers 0/1)
static const int O_XH    = 4864256;  // 800000 f region = 1.6M bf16 (layer-2 x copy)
static const int O_ASRC  = 5664256;  // 200000 f
static const int O_ADST  = 5864256;  // 200000 f
static const int O_AGG   = 6064256;  // 1.6M f
static const int O_X     = 7664256;  // 1.6M f
static const int O_BSWC  = 9264256;  // 2560 f = 5120 bf16
static const int O_BSWA  = 9266816;  // 512 f = 1024 bf16
static const int O_BSUM  = 9267328;  // 104 ints
static const int O_BOFF  = 9267432;  // 104 ints

using f32x4 = __attribute__((ext_vector_type(4))) float;
using sh8   = __attribute__((ext_vector_type(8))) short;  // 8 bf16

__device__ inline short f2bf(float f) {
    unsigned u = __float_as_uint(f);
    unsigned r = (u + 0x7FFFu + ((u >> 16) & 1u)) >> 16;   // RNE to bf16
    return (short)r;
}
__device__ inline float bf2f(unsigned short u) {
    return __uint_as_float(((unsigned)u) << 16);
}

// ============ setup: instats | goff | prew x3 | bswz | bswc | bswa ============
__global__ void k_pre(const int* __restrict__ batch, const float* __restrict__ x3,
                      const float* w0, const float* we0, const float* as0, const float* ad0, const float* ae0,
                      const float* w1, const float* we1, const float* as1, const float* ad1, const float* ae1,
                      const float* w2, const float* we2, const float* as2, const float* ad2, const float* ae2,
                      int* __restrict__ goff, float* __restrict__ ipart,
                      float* __restrict__ Ws, float* __restrict__ Wd, float* __restrict__ wev,
                      short* __restrict__ bsw, short* __restrict__ bswc, short* __restrict__ bswa) {
    __shared__ float sd[1536];
    int b = blockIdx.x, t = threadIdx.x;
    if (b < 16) {                         // input-BN partial stats
        int ib = b;
        float s[3] = {0,0,0}, q[3] = {0,0,0};
        for (int n = ib * 256 + t; n < NN; n += 16 * 256) {
#pragma unroll
            for (int i = 0; i < 3; i++) { float v = x3[n*3+i]; s[i] += v; q[i] += v*v; }
        }
#pragma unroll
        for (int i = 0; i < 3; i++) { sd[t*6+i] = s[i]; sd[t*6+3+i] = q[i]; }
        __syncthreads();
        for (int off = 128; off > 0; off >>= 1) {
            if (t < off) {
#pragma unroll
                for (int i = 0; i < 6; i++) sd[t*6+i] += sd[(t+off)*6+i];
            }
            __syncthreads();
        }
        if (t < 6) ipart[ib*6 + t] = sd[t];
    } else if (b == 16) {                 // graph offsets (batch sorted)
        if (t <= GG) {
            int g = t, lo = 0, hi = NN;
            while (lo < hi) { int mid = (lo + hi) >> 1; if (batch[mid] < g) lo = mid + 1; else hi = mid; }
            goff[g] = lo;
        }
    } else if (b < 20) {                  // per-layer attention weight fold
        int L = b - 17;
        const float *W, *Wep, *as_, *ad_, *ae_; int INF, CC;
        if (L == 0)      { W = w0; Wep = we0; as_ = as0; ad_ = ad0; ae_ = ae0; INF = 3;  CC = 8;  }
        else if (L == 1) { W = w1; Wep = we1; as_ = as1; ad_ = ad1; ae_ = ae1; INF = 64; CC = 8;  }
        else             { W = w2; Wep = we2; as_ = as2; ad_ = ad2; ae_ = ae2; INF = 64; CC = 64; }
        int HC = 8 * CC;
        for (int tt = t; tt < INF * 8; tt += 256) {
            int i = tt >> 3, h = tt & 7;
            float s = 0.f, d = 0.f;
            for (int c = 0; c < CC; c++) {
                float w = W[i*HC + h*CC + c];
                s += w * as_[h*CC + c];
                d += w * ad_[h*CC + c];
            }
            Ws[L*512 + i*8 + h] = s; Wd[L*512 + i*8 + h] = d;
        }
        if (t < 8) {
            float s = 0.f;
            for (int c = 0; c < CC; c++) s += Wep[t*CC + c] * ae_[t*CC + c];
            wev[L*8 + t] = s;
        }
    } else if (b < 148) {                 // W2 swizzle (128 blocks)
        int idx = (b - 20) * 256 + t;     // < 32768
        int j  = idx & 7;
        int l  = (idx >> 3) & 63;
        int nt = (idx >> 9) & 3;
        int kb = idx >> 11;
        int k = kb*32 + (l >> 4)*4 + (j & 3) + 16*(j >> 2);
        int c = nt*16 + (l & 15);
        int h = k >> 6, i = k & 63;
        bsw[idx] = f2bf(w2[i*512 + h*64 + c]);
    } else if (b < 168) {                 // layer-1 cat [W1|Ws1|Wd1] swizzle (20 blocks)
        int idx = (b - 148) * 256 + t;    // < 5120
        int j  = idx & 7;
        int l  = (idx >> 3) & 63;
        int r2 = idx >> 9;                // 0..9
        int nt = r2 % 5, kb = r2 / 5;
        int k = kb*32 + (l >> 4)*4 + (j & 3) + 16*(j >> 2);
        int c = nt*16 + (l & 15);
        float val;
        if (c < 64) val = w1[k*64 + c];
        else {
            int h = (c - 64) & 7;
            const float* aa = (c < 72) ? as1 : ad1;
            float s = 0.f;
            for (int cc = 0; cc < 8; cc++) s += w1[k*64 + h*8 + cc] * aa[h*8 + cc];
            val = s;
        }
        bswc[idx] = f2bf(val);
    } else {                              // layer-2 [Ws2|Wd2] swizzle (4 blocks)
        int idx = (b - 168) * 256 + t;    // < 1024
        int j  = idx & 7;
        int l  = (idx >> 3) & 63;
        int kb = idx >> 9;                // 0..1
        int k = kb*32 + (l >> 4)*4 + (j & 3) + 16*(j >> 2);
        int c = l & 15;
        int h = c & 7;
        const float* aa = (c < 8) ? as2 : ad2;
        float s = 0.f;
        for (int cc = 0; cc < 64; cc++) s += w2[k*512 + h*64 + cc] * aa[h*64 + cc];
        bswa[idx] = f2bf(s);
    }
}

// ============ edge histogram: per-block private LDS histogram, zero global atomics ============
__global__ __launch_bounds__(256) void k_hist(const int* __restrict__ ei, int* __restrict__ cnt) {
    __shared__ int hb[PL];
    int t = threadIdx.x, b = blockIdx.x;
    for (int i = t; i < PL; i += 256) hb[i] = 0;
    __syncthreads();
    int e0 = b * EPB;
    for (int e = e0 + t; e < e0 + EPB; e += 256)
        atomicAdd(&hb[ei[EE + e]], 1);
    __syncthreads();
    for (int i = t; i < NN; i += 256) cnt[b * PL + i] = hb[i];
}

// ============ hierarchical degree scan ============
__global__ void k_scan1(const int* __restrict__ cnt, int* __restrict__ rows,
                        int* __restrict__ bsum) {
    int t = threadIdx.x, b = blockIdx.x;
    int i = b * 256 + t;
    int v = 0;
    if (i < NN) {
        for (int r = 0; r < NB; r++) v += cnt[r * PL + i];
    }
    __shared__ int sd[256];
    sd[t] = v; __syncthreads();
    for (int off = 1; off < 256; off <<= 1) {
        int x = (t >= off) ? sd[t - off] : 0;
        __syncthreads();
        sd[t] += x;
        __syncthreads();
    }
    if (i < NN) rows[i] = sd[t] - v;     // exclusive local scan
    if (t == 255) bsum[b] = sd[255];
}

__global__ void k_scan2(const int* __restrict__ bsum, int* __restrict__ boff,
                        const float* __restrict__ ipart, float* __restrict__ inbn) {
    int t = threadIdx.x;
    if (t == 0) {
        int run = 0;
        for (int b = 0; b < 98; b++) { int v = bsum[b]; boff[b] = run; run += v; }
    }
    if (t < 6) { float s = 0.f; for (int b = 0; b < 16; b++) s += ipart[b*6 + t]; inbn[t] = s; }
}

__global__ void k_scan3(const int* __restrict__ boff, const int* __restrict__ cnt,
                        int* __restrict__ rows, int* __restrict__ cur) {
    int t = threadIdx.x, b = blockIdx.x;
    int i = b * 256 + t;
    if (i < NN) {
        int run = rows[i] + boff[b];
        rows[i] = run;
        for (int r = 0; r < NB; r++) {
            cur[r * PL + i] = run;
            run += cnt[r * PL + i];
        }
    }
    if (b == 0 && t == 0) rows[NN] = EE;
}

// ============ CSR fill: LDS cursor per block, zero global atomics ============
__global__ __launch_bounds__(256) void k_fill(const int* __restrict__ ei, const float* __restrict__ ea,
                       const int* __restrict__ cur, int* __restrict__ csrc,
                       float* __restrict__ cea) {
    __shared__ int lc[PL];
    int t = threadIdx.x, b = blockIdx.x;
    for (int i = t; i < NN; i += 256) lc[i] = cur[b * PL + i];
    __syncthreads();
    int e0 = b * EPB;
    for (int e = e0 + t; e < e0 + EPB; e += 256) {
        int s = ei[e], d = ei[EE + e];
        int pos = atomicAdd(&lc[d], 1);
        csrc[pos] = s; cea[pos] = ea[e];
    }
}

// ============ layer-0 projection (input BN fused, in=3); xs stored bf16 ============
__global__ void k_proj0(const float* __restrict__ x, const float* __restrict__ sums,
                        const float* __restrict__ g, const float* __restrict__ b,
                        const float* __restrict__ W0,
                        const float* __restrict__ Ws, const float* __restrict__ Wd,
                        unsigned short* __restrict__ xs16,
                        float* __restrict__ asrc, float* __restrict__ adst) {
    int idx = blockIdx.x * 256 + threadIdx.x;
    if (idx >= NN * 64) return;
    int n = idx >> 6, j = idx & 63;
    float xn[3];
#pragma unroll
    for (int i = 0; i < 3; i++) {
        float m = sums[i] * (1.0f / NN);
        float v = sums[3+i] * (1.0f / NN) - m*m;
        xn[i] = (x[n*3+i] - m) * rsqrtf(v + 1e-5f) * g[i] + b[i];
    }
    float a = 0.f;
#pragma unroll
    for (int i = 0; i < 3; i++) a += xn[i] * W0[i*64 + j];
    xs16[n*64 + j] = (unsigned short)f2bf(a);
    if (j < 16) {
        const float* WA = (j < 8) ? Ws : Wd;
        int h = j & 7;
        float s = 0.f;
#pragma unroll
        for (int i = 0; i < 3; i++) s += xn[i] * WA[i*8 + h];
        if (j < 8) asrc[n*8 + h] = s; else adst[n*8 + h] = s;
    }
}

// ============ fused edge-softmax + aggregation, C=8 (layers 0,1); bf16 gathers ============
__global__ void k_agg8f(const int* __restrict__ rows, const int* __restrict__ csrc,
                        const float* __restrict__ cea,
                        const float* __restrict__ asrc, const float* __restrict__ adst,
                        const float* __restrict__ wev,
                        const unsigned short* __restrict__ xs16, float* __restrict__ agg) {
    int lane = threadIdx.x & 63;
    int d = (blockIdx.x * blockDim.x + threadIdx.x) >> 6;
    if (d >= NN) return;
    int h = lane >> 3;
    float adh = adst[d*8 + h];
    float wh  = wev[h];
    int rs = rows[d], re = rows[d+1];
    float acc = 0.f, den = 0.f;
    for (int c0 = rs; c0 < re; c0 += 64) {
        int cnt = re - c0; if (cnt > 64) cnt = 64;
        int ii = c0 + (lane < cnt ? lane : 0);
        int es = csrc[ii];
        float ef = cea[ii];
        int j = 0;
        for (; j + 3 < cnt; j += 4) {
            int s0 = __shfl(es, j),   s1 = __shfl(es, j+1);
            int s2 = __shfl(es, j+2), s3 = __shfl(es, j+3);
            float a0 = __shfl(ef, j),   a1 = __shfl(ef, j+1);
            float a2 = __shfl(ef, j+2), a3 = __shfl(ef, j+3);
            float l0 = asrc[s0*8+h], l1 = asrc[s1*8+h];
            float l2 = asrc[s2*8+h], l3 = asrc[s3*8+h];
            float x0 = bf2f(xs16[s0*64+lane]), x1 = bf2f(xs16[s1*64+lane]);
            float x2 = bf2f(xs16[s2*64+lane]), x3 = bf2f(xs16[s3*64+lane]);
            l0 += adh + a0*wh; l1 += adh + a1*wh;
            l2 += adh + a2*wh; l3 += adh + a3*wh;
            l0 = fmaxf(l0, 0.2f*l0); l1 = fmaxf(l1, 0.2f*l1);
            l2 = fmaxf(l2, 0.2f*l2); l3 = fmaxf(l3, 0.2f*l3);
            float e0 = __expf(l0), e1 = __expf(l1), e2 = __expf(l2), e3 = __expf(l3);
            den += (e0 + e1) + (e2 + e3);
            acc += e0*x0; acc += e1*x1; acc += e2*x2; acc += e3*x3;
        }
        for (; j < cnt; j++) {
            int s = __shfl(es, j);
            float a = __shfl(ef, j);
            float l = asrc[s*8+h] + adh + a*wh;
            l = fmaxf(l, 0.2f*l);
            float e = __expf(l);
            den += e;
            acc += e * bf2f(xs16[s*64+lane]);
        }
    }
    agg[d*64 + lane] = acc / fmaxf(den, 1e-16f);
}

// ============ layer-1 projection via MFMA; xs stored bf16 ============
__global__ void k_proj1m(const float* __restrict__ agg, const float* __restrict__ ab,
                         const short* __restrict__ bswc,
                         float* __restrict__ xb, unsigned short* __restrict__ xs16,
                         float* __restrict__ asrc, float* __restrict__ adst) {
    int l = threadIdx.x & 63;
    int wid = (blockIdx.x * blockDim.x + threadIdx.x) >> 6;
    int n0 = wid * 16;
    if (n0 >= NN) return;
    int ra = n0 + (l & 15); if (ra > NN-1) ra = NN-1;
    int kq = (l >> 4) * 4;
    const sh8* Bs = (const sh8*)bswc;
    sh8 af0, af1;
#pragma unroll
    for (int kb = 0; kb < 2; kb++) {
        int c0 = kb*32 + kq;
        float4 a0 = *(const float4*)&agg[ra*64 + c0];
        float4 a1 = *(const float4*)&agg[ra*64 + c0 + 16];
        float4 sc0 = *(const float4*)&ab[c0];
        float4 sh0 = *(const float4*)&ab[64 + c0];
        float4 sc1 = *(const float4*)&ab[c0 + 16];
        float4 sh1 = *(const float4*)&ab[64 + c0 + 16];
        float o[8];
        o[0] = a0.x*sc0.x + sh0.x; o[1] = a0.y*sc0.y + sh0.y;
        o[2] = a0.z*sc0.z + sh0.z; o[3] = a0.w*sc0.w + sh0.w;
        o[4] = a1.x*sc1.x + sh1.x; o[5] = a1.y*sc1.y + sh1.y;
        o[6] = a1.z*sc1.z + sh1.z; o[7] = a1.w*sc1.w + sh1.w;
#pragma unroll
        for (int u = 0; u < 8; u++) o[u] = (o[u] > 0.f) ? o[u] : (__expf(o[u]) - 1.f);
        float4 w0v = {o[0],o[1],o[2],o[3]}, w1v = {o[4],o[5],o[6],o[7]};
        *(float4*)&xb[ra*64 + c0]      = w0v;
        *(float4*)&xb[ra*64 + c0 + 16] = w1v;
        sh8 af;
#pragma unroll
        for (int u = 0; u < 8; u++) af[u] = f2bf(o[u]);
        if (kb == 0) af0 = af; else af1 = af;
    }
    f32x4 acc[5];
#pragma unroll
    for (int nt = 0; nt < 5; nt++) acc[nt] = (f32x4){0,0,0,0};
#pragma unroll
    for (int nt = 0; nt < 5; nt++) {
        acc[nt] = __builtin_amdgcn_mfma_f32_16x16x32_bf16(af0, Bs[nt*64 + l], acc[nt], 0, 0, 0);
        acc[nt] = __builtin_amdgcn_mfma_f32_16x16x32_bf16(af1, Bs[(5+nt)*64 + l], acc[nt], 0, 0, 0);
    }
    int rbase = n0 + (l >> 4) * 4, cb = l & 15;
#pragma unroll
    for (int r = 0; r < 4; r++) {
        int n = rbase + r;
        if (n >= NN) break;
#pragma unroll
        for (int nt = 0; nt < 4; nt++)
            xs16[n*64 + nt*16 + cb] = (unsigned short)f2bf(acc[nt][r]);
        if (cb < 8) asrc[n*8 + cb] = acc[4][r];
        else        adst[n*8 + (cb-8)] = acc[4][r];
    }
}

// ============ fused BN1-apply + residual + layer-2 logits (MFMA) + bf16 x copy ============
__global__ void k_bnattn(const float* __restrict__ agg, const float* __restrict__ ab,
                         const short* __restrict__ bswa,
                         float* __restrict__ xb, unsigned short* __restrict__ xh16,
                         float* __restrict__ asrc, float* __restrict__ adst) {
    int l = threadIdx.x & 63;
    int wid = (blockIdx.x * blockDim.x + threadIdx.x) >> 6;
    int n0 = wid * 16;
    if (n0 >= NN) return;
    int ra = n0 + (l & 15); if (ra > NN-1) ra = NN-1;
    int kq = (l >> 4) * 4;
    const sh8* Bs = (const sh8*)bswa;
    sh8 af0, af1;
#pragma unroll
    for (int kb = 0; kb < 2; kb++) {
        int c0 = kb*32 + kq;
        float4 a0 = *(const float4*)&agg[ra*64 + c0];
        float4 a1 = *(const float4*)&agg[ra*64 + c0 + 16];
        float4 x0 = *(const float4*)&xb[ra*64 + c0];
        float4 x1 = *(const float4*)&xb[ra*64 + c0 + 16];
        float4 sc0 = *(const float4*)&ab[c0];
        float4 sh0 = *(const float4*)&ab[64 + c0];
        float4 sc1 = *(const float4*)&ab[c0 + 16];
        float4 sh1 = *(const float4*)&ab[64 + c0 + 16];
        float o[8];
        o[0] = a0.x*sc0.x + sh0.x; o[1] = a0.y*sc0.y + sh0.y;
        o[2] = a0.z*sc0.z + sh0.z; o[3] = a0.w*sc0.w + sh0.w;
        o[4] = a1.x*sc1.x + sh1.x; o[5] = a1.y*sc1.y + sh1.y;
        o[6] = a1.z*sc1.z + sh1.z; o[7] = a1.w*sc1.w + sh1.w;
#pragma unroll
        for (int u = 0; u < 8; u++) o[u] = (o[u] > 0.f) ? o[u] : (__expf(o[u]) - 1.f);
        o[0] += x0.x; o[1] += x0.y; o[2] += x0.z; o[3] += x0.w;
        o[4] += x1.x; o[5] += x1.y; o[6] += x1.z; o[7] += x1.w;
        float4 w0v = {o[0],o[1],o[2],o[3]}, w1v = {o[4],o[5],o[6],o[7]};
        *(float4*)&xb[ra*64 + c0]      = w0v;
        *(float4*)&xb[ra*64 + c0 + 16] = w1v;
        short4 h0, h1;
        h0.x = f2bf(o[0]); h0.y = f2bf(o[1]); h0.z = f2bf(o[2]); h0.w = f2bf(o[3]);
        h1.x = f2bf(o[4]); h1.y = f2bf(o[5]); h1.z = f2bf(o[6]); h1.w = f2bf(o[7]);
        *(short4*)&xh16[ra*64 + c0]      = h0;
        *(short4*)&xh16[ra*64 + c0 + 16] = h1;
        sh8 af;
#pragma unroll
        for (int u = 0; u < 8; u++) af[u] = f2bf(o[u]);
        if (kb == 0) af0 = af; else af1 = af;
    }
    f32x4 acc = {0,0,0,0};
    acc = __builtin_amdgcn_mfma_f32_16x16x32_bf16(af0, Bs[l],      acc, 0, 0, 0);
    acc = __builtin_amdgcn_mfma_f32_16x16x32_bf16(af1, Bs[64 + l], acc, 0, 0, 0);
    int rbase = n0 + (l >> 4) * 4, cb = l & 15;
#pragma unroll
    for (int r = 0; r < 4; r++) {
        int n = rbase + r;
        if (n >= NN) break;
        if (cb < 8) asrc[n*8 + cb] = acc[r];
        else        adst[n*8 + (cb-8)] = acc[r];
    }
}

// ============ layer-2 fused: edge-softmax + aggregate + MFMA; bf16 gathers ============
// 16 waves/block, one node per wave (best-measured config), 2x edge unroll.
__global__ __launch_bounds__(1024) void k_l2f(
        const int* __restrict__ rows, const int* __restrict__ csrc,
        const float* __restrict__ cea,
        const float* __restrict__ asrc, const float* __restrict__ adst,
        const float* __restrict__ wev,
        const unsigned short* __restrict__ xh16, const short* __restrict__ bsw,
        float* __restrict__ agg) {
    __shared__ short zl[16 * 520];
    int t = threadIdx.x, lane = t & 63, wv = t >> 6;   // wv in 0..15
    int blk = blockIdx.x;
    int h = lane >> 3;
    float wh = wev[h];
    const sh8* xh8 = (const sh8*)xh16;
    int fo8  = lane & 7;                 // which 8-feature group this lane owns
    int kb_w = lane >> 2;
    int qd0  = 2 * (lane & 1);
    int jhi  = 4 * ((lane >> 1) & 1);
    int r = wv;
    int d = blk * 16 + r;
    float acc[8] = {0,0,0,0,0,0,0,0};
    float den = 0.f;
    if (d < NN) {
        float adh = adst[d*8 + h];
        int rs = rows[d], re = rows[d+1];
        for (int c0 = rs; c0 < re; c0 += 64) {
            int cnt = re - c0; if (cnt > 64) cnt = 64;
            int ii = c0 + (lane < cnt ? lane : 0);
            int es = csrc[ii];
            float ef = cea[ii];
            int j = 0;
            for (; j + 1 < cnt; j += 2) {
                int s0 = __shfl(es, j), s1 = __shfl(es, j+1);
                float a0 = __shfl(ef, j), a1 = __shfl(ef, j+1);
                float l0 = asrc[s0*8+h], l1 = asrc[s1*8+h];
                sh8 u8 = xh8[s0*8 + fo8];
                sh8 v8 = xh8[s1*8 + fo8];
                l0 += adh + a0*wh; l1 += adh + a1*wh;
                l0 = fmaxf(l0, 0.2f*l0); l1 = fmaxf(l1, 0.2f*l1);
                float e0 = __expf(l0), e1 = __expf(l1);
                den += e0 + e1;
#pragma unroll
                for (int u = 0; u < 8; u++)
                    acc[u] += e0 * bf2f((unsigned short)u8[u]) + e1 * bf2f((unsigned short)v8[u]);
            }
            if (j < cnt) {
                int s = __shfl(es, j);
                float a = __shfl(ef, j);
                float l = asrc[s*8+h] + adh + a*wh;
                l = fmaxf(l, 0.2f*l);
                float e = __expf(l);
                den += e;
                sh8 u8 = xh8[s*8 + fo8];
#pragma unroll
                for (int u = 0; u < 8; u++)
                    acc[u] += e * bf2f((unsigned short)u8[u]);
            }
        }
    }
    float inv = 1.0f / fmaxf(den, 1e-16f);
    short4 lo, hi;
    lo.x = f2bf(acc[0]*inv); lo.y = f2bf(acc[1]*inv);
    lo.z = f2bf(acc[2]*inv); lo.w = f2bf(acc[3]*inv);
    hi.x = f2bf(acc[4]*inv); hi.y = f2bf(acc[5]*inv);
    hi.z = f2bf(acc[6]*inv); hi.w = f2bf(acc[7]*inv);
    *(short4*)&zl[kb_w*520 + (r + 16*qd0)*8 + jhi]     = lo;
    *(short4*)&zl[kb_w*520 + (r + 16*(qd0+1))*8 + jhi] = hi;
    __syncthreads();
    if (wv < 4) {
        const sh8* Bs = (const sh8*)bsw;
        f32x4 oacc = {0,0,0,0};
        for (int kb = 0; kb < 16; kb++) {
            sh8 a = *(const sh8*)&zl[kb*520 + lane*8];
            sh8 bf = Bs[(kb*4 + wv)*64 + lane];
            oacc = __builtin_amdgcn_mfma_f32_16x16x32_bf16(a, bf, oacc, 0, 0, 0);
        }
        int row = blk*16 + (lane >> 4) * 4;
        int col = wv*16 + (lane & 15);
#pragma unroll
        for (int rr = 0; rr < 4; rr++) {
            int n = row + rr;
            if (n < NN) agg[(size_t)n*64 + col] = oacc[rr] * 0.125f;
        }
    }
}

// ============ BN stats partials (bias cancels in training-mode BN) ============
__global__ void k_bnstats(const float* __restrict__ agg, float* __restrict__ part) {
    int t = threadIdx.x;
    int c = t & 63;
    int r0 = blockIdx.x * 4 + (t >> 6);
    float s = 0.f, q = 0.f;
    for (int n = r0; n < NN; n += gridDim.x * 4) {
        float y = agg[n*64 + c];
        s += y; q += y*y;
    }
    __shared__ float sd[512];
    sd[t] = s; sd[256 + t] = q;
    __syncthreads();
    if (t < 128) { sd[t] += sd[t+128]; sd[256+t] += sd[256+t+128]; }
    __syncthreads();
    if (t < 64) {
        part[blockIdx.x*128 + t]      = sd[t] + sd[t+64];
        part[blockIdx.x*128 + 64 + t] = sd[256+t] + sd[256+t+64];
    }
}

// ============ BN finalize ============
__global__ void k_bnfin(const float* __restrict__ part, const float* __restrict__ gam,
                        const float* __restrict__ bet, float* __restrict__ ab) {
    int c = threadIdx.x;
    if (c >= 64) return;
    float s = 0.f, q = 0.f;
    for (int b = 0; b < 128; b++) { s += part[b*128 + c]; q += part[b*128 + 64 + c]; }
    float m = s * (1.0f / NN);
    float v = q * (1.0f / NN) - m*m;
    float a = gam[c] * rsqrtf(v + 1e-5f);
    ab[c] = a;
    ab[64 + c] = bet[c] - m * a;
}

// ============ fused: BN2-apply + residual + dual pooling + MLP head ============
__global__ void k_poolmlp(const float* __restrict__ xb, const float* __restrict__ agg,
                          const float* __restrict__ ab, const int* __restrict__ goff,
                          const float* __restrict__ fc1w, const float* __restrict__ fc1b,
                          const float* __restrict__ fc2w, const float* __restrict__ fc2b,
                          const float* __restrict__ fgw, const float* __restrict__ fgb,
                          const float* __restrict__ fbw, const float* __restrict__ fbb,
                          float* __restrict__ out) {
    int g = blockIdx.x, t = threadIdx.x;
    int c = t & 63, r = t >> 6;
    float a = ab[c], sh = ab[64 + c];
    int st = goff[g], en = goff[g+1];
    float s = 0.f, mx = -INFINITY;
    for (int n = st + r; n < en; n += 4) {
        float o = agg[n*64 + c] * a + sh;
        o = (o > 0.f) ? o : (__expf(o) - 1.0f);
        float v = xb[n*64 + c] + o;
        s += v; mx = fmaxf(mx, v);
    }
    __shared__ float sd[512];
    __shared__ float sg[128], s1[128], s2[64];
    sd[t] = s; sd[256 + t] = mx;
    __syncthreads();
    if (t < 128) { sd[t] += sd[t+128]; sd[256+t] = fmaxf(sd[256+t], sd[256+t+128]); }
    __syncthreads();
    if (t < 64) {
        float cnt = (float)(en - st);
        sg[t]      = (sd[t] + sd[t+64]) / fmaxf(cnt, 1.0f);
        sg[64 + t] = fmaxf(sd[256+t], sd[256+t+64]);
    }
    __syncthreads();
    if (t < 128) {
        float av = fc1b[t];
        for (int i = 0; i < 128; i++) av += sg[i] * fc1w[i*128 + t];
        s1[t] = (av > 0.f) ? av : (__expf(av) - 1.f);
    }
    __syncthreads();
    if (t < 64) {
        float bv = fc2b[t];
        for (int i = 0; i < 128; i++) bv += s1[i] * fc2w[i*64 + t];
        s2[t] = (bv > 0.f) ? bv : (__expf(bv) - 1.f);
    }
    __syncthreads();
    if (t == 0) {
        float ga = fgb[0], be = fbb[0];
        for (int i = 0; i < 64; i++) { ga += s2[i] * fgw[i]; be += s2[i] * fbw[i]; }
        out[g*2 + 0] = ga;
        out[g*2 + 1] = be;
    }
}

extern "C" void kernel_launch(void* const* d_in, const int* in_sizes, int n_in,
                              void* d_out, int out_size, void* d_ws, size_t ws_size,
                              hipStream_t stream) {
    (void)in_sizes; (void)n_in; (void)out_size; (void)ws_size;
    const float* x3    = (const float*)d_in[0];
    const int*   ei    = (const int*)d_in[1];
    const float* ea    = (const float*)d_in[2];
    const int*   batch = (const int*)d_in[3];
    const float* ing   = (const float*)d_in[4];
    const float* inb   = (const float*)d_in[5];
    const float* w0    = (const float*)d_in[6];
    const float* we0   = (const float*)d_in[7];
    const float* as0   = (const float*)d_in[8];
    const float* ad0   = (const float*)d_in[9];
    const float* ae0   = (const float*)d_in[10];
    const float* bng0  = (const float*)d_in[12];
    const float* bnb0  = (const float*)d_in[13];
    const float* w1    = (const float*)d_in[14];
    const float* we1   = (const float*)d_in[15];
    const float* as1   = (const float*)d_in[16];
    const float* ad1   = (const float*)d_in[17];
    const float* ae1   = (const float*)d_in[18];
    const float* bng1  = (const float*)d_in[20];
    const float* bnb1  = (const float*)d_in[21];
    const float* w2    = (const float*)d_in[22];
    const float* we2   = (const float*)d_in[23];
    const float* as2   = (const float*)d_in[24];
    const float* ad2   = (const float*)d_in[25];
    const float* ae2   = (const float*)d_in[26];
    const float* bng2  = (const float*)d_in[28];
    const float* bnb2  = (const float*)d_in[29];
    const float* fc1w  = (const float*)d_in[30];
    const float* fc1b  = (const float*)d_in[31];
    const float* fc2w  = (const float*)d_in[32];
    const float* fc2b  = (const float*)d_in[33];
    const float* fgw   = (const float*)d_in[34];
    const float* fgb   = (const float*)d_in[35];
    const float* fbw   = (const float*)d_in[36];
    const float* fbb   = (const float*)d_in[37];

    float* fws = (float*)d_ws;
    int*   iws = (int*)d_ws;
    int*   cnt   = iws + O_CNT;
    int*   rows  = iws + O_ROWS;
    int*   cur   = iws + O_CUR;
    int*   goff  = iws + O_GOFF;
    float* ipart = fws + O_IPART;
    float* inbn  = fws + O_INBN;
    float* Ws    = fws + O_WS;
    float* Wd    = fws + O_WD;
    float* wev   = fws + O_WE;
    float* bpart = fws + O_BPART;
    float* ab    = fws + O_AB;
    short* bsw   = (short*)(fws + O_BSW);
    int*   csrc  = iws + O_CSRC;
    float* cea   = fws + O_CEA;
    unsigned short* xs16 = (unsigned short*)(fws + O_XS);
    unsigned short* xh16 = (unsigned short*)(fws + O_XH);
    float* asrc  = fws + O_ASRC;
    float* adst  = fws + O_ADST;
    float* agg   = fws + O_AGG;
    float* xb    = fws + O_X;
    short* bswc  = (short*)(fws + O_BSWC);
    short* bswa  = (short*)(fws + O_BSWA);
    int*   bsum  = iws + O_BSUM;
    int*   boff  = iws + O_BOFF;

    k_pre<<<172, 256, 0, stream>>>(batch, x3,
                                   w0, we0, as0, ad0, ae0,
                                   w1, we1, as1, ad1, ae1,
                                   w2, we2, as2, ad2, ae2,
                                   goff, ipart, Ws, Wd, wev, bsw, bswc, bswa);
    k_hist<<<NB, 256, 0, stream>>>(ei, cnt);
    k_scan1<<<98, 256, 0, stream>>>(cnt, rows, bsum);
    k_scan2<<<1, 64, 0, stream>>>(bsum, boff, ipart, inbn);
    k_scan3<<<98, 256, 0, stream>>>(boff, cnt, rows, cur);
    k_fill<<<NB, 256, 0, stream>>>(ei, ea, cur, csrc, cea);

    const int nblk64 = (NN * 64 + 255) / 256;   // 6250
    const int wblk16 = ((NN + 15) / 16 + 3) / 4; // 391 blocks of 4 waves (16 nodes/wave)

    // ---- layer 0 ----
    k_proj0<<<nblk64, 256, 0, stream>>>(x3, inbn, ing, inb, w0, Ws, Wd, xs16, asrc, adst);
    k_agg8f<<<nblk64, 256, 0, stream>>>(rows, csrc, cea, asrc, adst, wev, xs16, agg);
    k_bnstats<<<128, 256, 0, stream>>>(agg, bpart);
    k_bnfin<<<1, 64, 0, stream>>>(bpart, bng0, bnb0, ab);

    // ---- layer 1 (BN0-apply + xb + projection + logits via MFMA) ----
    k_proj1m<<<wblk16, 256, 0, stream>>>(agg, ab, bswc, xb, xs16, asrc, adst);
    k_agg8f<<<nblk64, 256, 0, stream>>>(rows, csrc, cea, asrc, adst, wev + 8, xs16, agg);
    k_bnstats<<<128, 256, 0, stream>>>(agg, bpart);
    k_bnfin<<<1, 64, 0, stream>>>(bpart, bng1, bnb1, ab);

    // ---- layer 2 (BN1-apply + residual + logits + bf16 copy; fused agg+MFMA) ----
    k_bnattn<<<wblk16, 256, 0, stream>>>(agg, ab, bswa, xb, xh16, asrc, adst);
    k_l2f<<<(NN + 15) / 16, 1024, 0, stream>>>(rows, csrc, cea, asrc, adst, wev + 16,
                                               xh16, bsw, agg);
    k_bnstats<<<128, 256, 0, stream>>>(agg, bpart);
    k_bnfin<<<1, 64, 0, stream>>>(bpart, bng2, bnb2, ab);

    // ---- BN2-apply + residual + pooling + MLP head ----
    k_poolmlp<<<GG, 256, 0, stream>>>(xb, agg, ab, goff, fc1w, fc1b, fc2w, fc2b,
                                      fgw, fgb, fbw, fbb, (float*)d_out);
}